// Round 1
// baseline (256.720 us; speedup 1.0000x reference)
//
#include <hip/hip_runtime.h>

typedef _Float16 half_t;
typedef __attribute__((ext_vector_type(8))) _Float16 f16x8;
typedef __attribute__((ext_vector_type(4))) _Float16 f16x4;
typedef __attribute__((ext_vector_type(4))) float f32x4;

#define DEVI __device__ __forceinline__

static constexpr int Bn = 4, Cc = 256, Nn = 4096, PD = 32;

// persistent f16 intermediates (module-scope device memory; fully rewritten every call)
__device__ half_t g_Q[(size_t)Bn * Nn * PD];   // [b][n][d]
__device__ half_t g_K[(size_t)Bn * Nn * PD];   // [b][n][d]  (= k^T)
__device__ half_t g_V[(size_t)Bn * Cc * Nn];   // [b][e][n]

DEVI f16x8 cvt8(float4 a, float4 b) {
    f16x8 r;
    r[0] = (_Float16)a.x; r[1] = (_Float16)a.y; r[2] = (_Float16)a.z; r[3] = (_Float16)a.w;
    r[4] = (_Float16)b.x; r[5] = (_Float16)b.y; r[6] = (_Float16)b.z; r[7] = (_Float16)b.w;
    return r;
}

// ---------------- projection: Q,K,V = W @ x (+bias), f16 outputs ----------------
__global__ __launch_bounds__(256, 1) void proj_kernel(
    const float* __restrict__ x,
    const float* __restrict__ Wq, const float* __restrict__ bq,
    const float* __restrict__ Wk, const float* __restrict__ bk,
    const float* __restrict__ Wv, const float* __restrict__ bv)
{
    __shared__ __align__(16) half_t xt[64 * 40];   // [n][c] tile, pad 32->40

    const int b    = blockIdx.x >> 6;
    const int n0   = (blockIdx.x & 63) * 64;
    const int t    = threadIdx.x;
    const int w    = t >> 6;
    const int lane = t & 63;
    const int l15  = lane & 15, g = lane >> 4;

    f32x4 qk_acc[4] = {};          // wave's 16 QK rows x 4 n-tiles
    f32x4 v_acc[4][4] = {};        // [et][nf]

    const float* wrow_qk = (w < 2) ? (Wq + (size_t)(16 * w + l15) * Cc)
                                   : (Wk + (size_t)(16 * (w - 2) + l15) * Cc);

    for (int cs = 0; cs < 8; ++cs) {
        const int c0 = cs * 32;
        // stage x tile: wave w loads its 8 c-rows for all 64 n (coalesced), f16 into LDS [n][c]
        {
            const int nl = t & 63;
            const int cg = t >> 6;
            const float* xp = x + ((size_t)(b * Cc + c0 + cg * 8)) * Nn + n0 + nl;
            float f[8];
#pragma unroll
            for (int q = 0; q < 8; ++q) f[q] = xp[(size_t)q * Nn];
            f16x4 h0, h1;
#pragma unroll
            for (int q = 0; q < 4; ++q) { h0[q] = (_Float16)f[q]; h1[q] = (_Float16)f[q + 4]; }
            *(f16x4*)&xt[nl * 40 + cg * 8]     = h0;
            *(f16x4*)&xt[nl * 40 + cg * 8 + 4] = h1;
        }
        __syncthreads();

        f16x8 xf[4];
#pragma unroll
        for (int nf = 0; nf < 4; ++nf)
            xf[nf] = *(const f16x8*)&xt[(nf * 16 + l15) * 40 + g * 8];

        // QK (straight: A=W rows, B=x)
        {
            const float* wp = wrow_qk + c0 + g * 8;
            const f16x8 af = cvt8(*(const float4*)wp, *(const float4*)(wp + 4));
#pragma unroll
            for (int nt = 0; nt < 4; ++nt)
                qk_acc[nt] = __builtin_amdgcn_mfma_f32_16x16x32_f16(af, xf[nt], qk_acc[nt], 0, 0, 0);
        }
        // V (swapped: A=x^T, B=Wv^T) -> D rows are n (packed stores to [e][n])
#pragma unroll
        for (int et = 0; et < 4; ++et) {
            const int e = (w * 4 + et) * 16 + l15;
            const float* wp = Wv + (size_t)e * Cc + c0 + g * 8;
            const f16x8 wf = cvt8(*(const float4*)wp, *(const float4*)(wp + 4));
#pragma unroll
            for (int nf = 0; nf < 4; ++nf)
                v_acc[et][nf] = __builtin_amdgcn_mfma_f32_16x16x32_f16(xf[nf], wf, v_acc[et][nf], 0, 0, 0);
        }
        __syncthreads();
    }

    // epilogue QK -> g_Q / g_K  [n][32], rows d = 16*(w&1)+4g+r
    {
        const float* bias = (w < 2) ? bq : bk;
        const int dbase = 16 * (w & 1) + 4 * g;
        float bb[4];
#pragma unroll
        for (int r = 0; r < 4; ++r) bb[r] = bias[dbase + r];
        half_t* dst = (w < 2) ? g_Q : g_K;
#pragma unroll
        for (int nt = 0; nt < 4; ++nt) {
            const int n = n0 + nt * 16 + l15;
            f16x4 h;
#pragma unroll
            for (int r = 0; r < 4; ++r) h[r] = (_Float16)(qk_acc[nt][r] + bb[r]);
            *(f16x4*)&dst[((size_t)b * Nn + n) * PD + dbase] = h;
        }
    }
    // epilogue V -> g_V [e][n], rows n = n0+nf*16+4g+r
#pragma unroll
    for (int et = 0; et < 4; ++et) {
        const int e = (w * 4 + et) * 16 + l15;
        const float bve = bv[e];
#pragma unroll
        for (int nf = 0; nf < 4; ++nf) {
            const int n = n0 + nf * 16 + 4 * g;
            f16x4 h;
#pragma unroll
            for (int r = 0; r < 4; ++r) h[r] = (_Float16)(v_acc[et][nf][r] + bve);
            *(f16x4*)&g_V[((size_t)b * Cc + e) * Nn + n] = h;
        }
    }
}

// ---------------- fused flash attention + residual ----------------
__global__ __launch_bounds__(256, 1) void attn_kernel(
    const float* __restrict__ x, const float* __restrict__ gamma_p, float* __restrict__ out)
{
    __shared__ __align__(16) half_t V_lds[Cc * 64];       // [e][n] swizzled, 32KB
    __shared__ __align__(16) half_t P_lds[4][16 * 64];    // per-wave [m][n] swizzled, 8KB

    const int b    = blockIdx.x >> 6;
    const int m0   = (blockIdx.x & 63) * 64;
    const int t    = threadIdx.x;
    const int w    = t >> 6;
    const int lane = t & 63;
    const int l15  = lane & 15, g = lane >> 4;

    const f16x8 qf = *(const f16x8*)&g_Q[((size_t)b * Nn + m0 + w * 16 + l15) * PD + g * 8];

    f32x4 acc[16] = {};
    float run_m = -1e30f, run_l = 0.f;

    const half_t* Kb = g_K + (size_t)b * Nn * PD;
    const half_t* Vb = g_V + (size_t)b * Cc * Nn;
    const int pmask = (l15 & 7) << 3;

    for (int i = 0; i < Nn / 64; ++i) {
        const int n0 = i * 64;

        // T14: issue V-tile global loads early (consumed after barrier)
        uint4 st[8];
        {
            const int er = t >> 3;
            const int j8 = (t & 7) * 8;
#pragma unroll
            for (int p = 0; p < 8; ++p)
                st[p] = *(const uint4*)&Vb[(size_t)(p * 32 + er) * Nn + n0 + j8];
        }

        // QK^T swapped: S^T tile, lane: col m = l15, rows n = 16t+4g+r
        f32x4 s[4];
        const f32x4 zero = {0.f, 0.f, 0.f, 0.f};
#pragma unroll
        for (int tt = 0; tt < 4; ++tt) {
            const f16x8 kf = *(const f16x8*)&Kb[(size_t)(n0 + tt * 16 + l15) * PD + g * 8];
            s[tt] = __builtin_amdgcn_mfma_f32_16x16x32_f16(kf, qf, zero, 0, 0, 0);
        }

        // online softmax for row m = l15 (reduce over g-groups only)
        float tm = s[0][0];
#pragma unroll
        for (int tt = 0; tt < 4; ++tt)
#pragma unroll
            for (int r = 0; r < 4; ++r) tm = fmaxf(tm, s[tt][r]);
        tm = fmaxf(tm, __shfl_xor(tm, 16));
        tm = fmaxf(tm, __shfl_xor(tm, 32));
        const float nm    = fmaxf(run_m, tm);
        const float alpha = __builtin_amdgcn_exp2f((run_m - nm) * 1.44269504089f);
        run_m = nm;

        float p[4][4];
        float rs = 0.f;
#pragma unroll
        for (int tt = 0; tt < 4; ++tt)
#pragma unroll
            for (int r = 0; r < 4; ++r) {
                p[tt][r] = __builtin_amdgcn_exp2f((s[tt][r] - nm) * 1.44269504089f);
                rs += p[tt][r];
            }
        rs += __shfl_xor(rs, 16);
        rs += __shfl_xor(rs, 32);
        run_l = run_l * alpha + rs;

        // write P tile (wave-local), swizzled
#pragma unroll
        for (int tt = 0; tt < 4; ++tt) {
            const int n = tt * 16 + 4 * g;
            f16x4 h;
#pragma unroll
            for (int r = 0; r < 4; ++r) h[r] = (_Float16)p[tt][r];
            *(f16x4*)&P_lds[w][l15 * 64 + (n ^ pmask)] = h;
        }

        // alpha for this lane's acc rows (m = 4g+r)
        float a4[4];
#pragma unroll
        for (int r = 0; r < 4; ++r) a4[r] = __shfl(alpha, 4 * g + r);

        __syncthreads();                       // prev PV reads of V_lds done
        {
            const int er = t >> 3;
            const int j8 = (t & 7) * 8;
#pragma unroll
            for (int p2 = 0; p2 < 8; ++p2) {
                const int e = p2 * 32 + er;
                *(uint4*)&V_lds[e * 64 + (j8 ^ ((e & 7) << 3))] = st[p2];
            }
        }
        __syncthreads();                       // V tile ready

#pragma unroll
        for (int et = 0; et < 16; ++et)
#pragma unroll
            for (int r = 0; r < 4; ++r) acc[et][r] *= a4[r];

        // PV: A = P[m][n], B = V[n][e] from [e][n]-swizzled LDS
        const f16x8 pf0 = *(const f16x8*)&P_lds[w][l15 * 64 + ((8 * g) ^ pmask)];
        const f16x8 pf1 = *(const f16x8*)&P_lds[w][l15 * 64 + ((32 + 8 * g) ^ pmask)];
#pragma unroll
        for (int et = 0; et < 16; ++et) {
            const int e = et * 16 + l15;
            const f16x8 vf0 = *(const f16x8*)&V_lds[e * 64 + ((8 * g) ^ ((e & 7) << 3))];
            const f16x8 vf1 = *(const f16x8*)&V_lds[e * 64 + ((32 + 8 * g) ^ ((e & 7) << 3))];
            acc[et] = __builtin_amdgcn_mfma_f32_16x16x32_f16(pf0, vf0, acc[et], 0, 0, 0);
            acc[et] = __builtin_amdgcn_mfma_f32_16x16x32_f16(pf1, vf1, acc[et], 0, 0, 0);
        }
    }

    // epilogue: normalize, gamma, residual; lane rows m = 4g+r (contig -> float4)
    const float gm = gamma_p[0];
    float inv[4];
#pragma unroll
    for (int r = 0; r < 4; ++r) inv[r] = 1.0f / __shfl(run_l, 4 * g + r);
#pragma unroll
    for (int et = 0; et < 16; ++et) {
        const int e = et * 16 + l15;
        const size_t idx = ((size_t)b * Cc + e) * Nn + (m0 + w * 16 + 4 * g);
        const float4 xin = *(const float4*)&x[idx];
        float4 o;
        o.x = gm * acc[et][0] * inv[0] + xin.x;
        o.y = gm * acc[et][1] * inv[1] + xin.y;
        o.z = gm * acc[et][2] * inv[2] + xin.z;
        o.w = gm * acc[et][3] * inv[3] + xin.w;
        *(float4*)&out[idx] = o;
    }
}

extern "C" void kernel_launch(void* const* d_in, const int* in_sizes, int n_in,
                              void* d_out, int out_size, void* d_ws, size_t ws_size,
                              hipStream_t stream) {
    (void)in_sizes; (void)n_in; (void)out_size; (void)d_ws; (void)ws_size;
    const float* x  = (const float*)d_in[0];
    const float* Wq = (const float*)d_in[1];
    const float* bq = (const float*)d_in[2];
    const float* Wk = (const float*)d_in[3];
    const float* bk = (const float*)d_in[4];
    const float* Wv = (const float*)d_in[5];
    const float* bv = (const float*)d_in[6];
    const float* gm = (const float*)d_in[7];
    float* out = (float*)d_out;

    proj_kernel<<<256, 256, 0, stream>>>(x, Wq, bq, Wk, bk, Wv, bv);
    attn_kernel<<<256, 256, 0, stream>>>(x, gm, out);
}

// Round 2
// 218.964 us; speedup vs baseline: 1.1724x; 1.1724x over previous
//
#include <hip/hip_runtime.h>

typedef _Float16 half_t;
typedef __attribute__((ext_vector_type(8))) _Float16 f16x8;
typedef __attribute__((ext_vector_type(4))) _Float16 f16x4;
typedef __attribute__((ext_vector_type(4))) float f32x4;

#define DEVI __device__ __forceinline__

static constexpr int Bn = 4, Cc = 256, Nn = 4096, PD = 32;

// persistent f16 intermediates (module-scope device memory; fully rewritten every call)
__device__ half_t g_Q[(size_t)Bn * Nn * PD];   // [b][n][d]
__device__ half_t g_K[(size_t)Bn * Nn * PD];   // [b][n][d]  (= k^T)
__device__ half_t g_V[(size_t)Bn * Cc * Nn];   // [b][e][n]

DEVI f16x8 cvt8(float4 a, float4 b) {
    f16x8 r;
    r[0] = (_Float16)a.x; r[1] = (_Float16)a.y; r[2] = (_Float16)a.z; r[3] = (_Float16)a.w;
    r[4] = (_Float16)b.x; r[5] = (_Float16)b.y; r[6] = (_Float16)b.z; r[7] = (_Float16)b.w;
    return r;
}

// ---------------- projection: Q,K,V = W @ x (+bias), f16 outputs ----------------
__global__ __launch_bounds__(256, 1) void proj_kernel(
    const float* __restrict__ x,
    const float* __restrict__ Wq, const float* __restrict__ bq,
    const float* __restrict__ Wk, const float* __restrict__ bk,
    const float* __restrict__ Wv, const float* __restrict__ bv)
{
    __shared__ __align__(16) half_t xt[64 * 40];   // [n][c] tile, pad 32->40

    const int b    = blockIdx.x >> 6;
    const int n0   = (blockIdx.x & 63) * 64;
    const int t    = threadIdx.x;
    const int w    = t >> 6;
    const int lane = t & 63;
    const int l15  = lane & 15, g = lane >> 4;

    f32x4 qk_acc[4] = {};          // wave's 16 QK rows x 4 n-tiles
    f32x4 v_acc[4][4] = {};        // [et][nf]

    const float* wrow_qk = (w < 2) ? (Wq + (size_t)(16 * w + l15) * Cc)
                                   : (Wk + (size_t)(16 * (w - 2) + l15) * Cc);

    for (int cs = 0; cs < 8; ++cs) {
        const int c0 = cs * 32;
        {
            const int nl = t & 63;
            const int cg = t >> 6;
            const float* xp = x + ((size_t)(b * Cc + c0 + cg * 8)) * Nn + n0 + nl;
            float f[8];
#pragma unroll
            for (int q = 0; q < 8; ++q) f[q] = xp[(size_t)q * Nn];
            f16x4 h0, h1;
#pragma unroll
            for (int q = 0; q < 4; ++q) { h0[q] = (_Float16)f[q]; h1[q] = (_Float16)f[q + 4]; }
            *(f16x4*)&xt[nl * 40 + cg * 8]     = h0;
            *(f16x4*)&xt[nl * 40 + cg * 8 + 4] = h1;
        }
        __syncthreads();

        f16x8 xf[4];
#pragma unroll
        for (int nf = 0; nf < 4; ++nf)
            xf[nf] = *(const f16x8*)&xt[(nf * 16 + l15) * 40 + g * 8];

        {
            const float* wp = wrow_qk + c0 + g * 8;
            const f16x8 af = cvt8(*(const float4*)wp, *(const float4*)(wp + 4));
#pragma unroll
            for (int nt = 0; nt < 4; ++nt)
                qk_acc[nt] = __builtin_amdgcn_mfma_f32_16x16x32_f16(af, xf[nt], qk_acc[nt], 0, 0, 0);
        }
#pragma unroll
        for (int et = 0; et < 4; ++et) {
            const int e = (w * 4 + et) * 16 + l15;
            const float* wp = Wv + (size_t)e * Cc + c0 + g * 8;
            const f16x8 wf = cvt8(*(const float4*)wp, *(const float4*)(wp + 4));
#pragma unroll
            for (int nf = 0; nf < 4; ++nf)
                v_acc[et][nf] = __builtin_amdgcn_mfma_f32_16x16x32_f16(xf[nf], wf, v_acc[et][nf], 0, 0, 0);
        }
        __syncthreads();
    }

    {
        const float* bias = (w < 2) ? bq : bk;
        const int dbase = 16 * (w & 1) + 4 * g;
        float bb[4];
#pragma unroll
        for (int r = 0; r < 4; ++r) bb[r] = bias[dbase + r];
        half_t* dst = (w < 2) ? g_Q : g_K;
#pragma unroll
        for (int nt = 0; nt < 4; ++nt) {
            const int n = n0 + nt * 16 + l15;
            f16x4 h;
#pragma unroll
            for (int r = 0; r < 4; ++r) h[r] = (_Float16)(qk_acc[nt][r] + bb[r]);
            *(f16x4*)&dst[((size_t)b * Nn + n) * PD + dbase] = h;
        }
    }
#pragma unroll
    for (int et = 0; et < 4; ++et) {
        const int e = (w * 4 + et) * 16 + l15;
        const float bve = bv[e];
#pragma unroll
        for (int nf = 0; nf < 4; ++nf) {
            const int n = n0 + nf * 16 + 4 * g;
            f16x4 h;
#pragma unroll
            for (int r = 0; r < 4; ++r) h[r] = (_Float16)(v_acc[et][nf][r] + bve);
            *(f16x4*)&g_V[((size_t)b * Cc + e) * Nn + n] = h;
        }
    }
}

// ---------------- fused flash attention + residual (v2: e-split waves) ----------------
// Block: 64 query rows (m0..m0+63) x all 256 e.  Wave w: QK+softmax for m-subtile w
// (16 rows), PV for ALL 64 m x its own 64 e-rows [64w,64w+64).  V slice is
// wave-private (no barrier needed); P/alpha shared via double-buffered LDS ->
// exactly ONE __syncthreads per KV tile.
__global__ __launch_bounds__(256, 1) void attn_kernel(
    const float* __restrict__ x, const float* __restrict__ gamma_p, float* __restrict__ out)
{
    __shared__ __align__(16) half_t Vb_lds[2][Cc * 64];   // [buf][e][n] swizzled, 64KB
    __shared__ __align__(16) half_t Pb_lds[2][64 * 64];   // [buf][m][n] swizzled, 16KB
    __shared__ float Ab[2][64];                           // alpha per m-row
    __shared__ float Lb[64];                              // final l per m-row

    const int b    = blockIdx.x >> 6;
    const int m0   = (blockIdx.x & 63) * 64;
    const int t    = threadIdx.x;
    const int w    = t >> 6;
    const int lane = t & 63;
    const int l15  = lane & 15, g = lane >> 4;

    const half_t* Kb  = g_K + (size_t)b * Nn * PD;
    const half_t* Vbg = g_V + (size_t)b * Cc * Nn;

    const f16x8 qf = *(const f16x8*)&g_Q[((size_t)b * Nn + m0 + w * 16 + l15) * PD + g * 8];

    // staging geometry (wave-private 64e x 64n slice)
    const int e_l  = lane >> 3;           // 0..7
    const int n8   = (lane & 7) * 8;      // element offset
    const int e0   = w * 64;
    const int wsw  = e_l << 3;            // write swizzle mask (elements), e&7 == e_l
    const int pmask = (l15 & 7) << 3;

    f32x4 acc[4][4] = {};                 // [mt][et], rows m=mt*16+4g+r, col e=e0+et*16+l15
    float run_m = -1e30f, run_l = 0.f;

    uint4 st[8];
    f16x8 kf_cur[4], kf_nxt[4];

    // prologue: V[0] -> LDS buf0 (wave-private), K[0] -> regs
#pragma unroll
    for (int p = 0; p < 8; ++p)
        st[p] = *(const uint4*)&Vbg[(size_t)(e0 + p * 8 + e_l) * Nn + n8];
#pragma unroll
    for (int tt = 0; tt < 4; ++tt)
        kf_cur[tt] = *(const f16x8*)&Kb[(size_t)(tt * 16 + l15) * PD + g * 8];
#pragma unroll
    for (int p = 0; p < 8; ++p)
        *(uint4*)&Vb_lds[0][(e0 + p * 8 + e_l) * 64 + (n8 ^ wsw)] = st[p];

    for (int i = 0; i < Nn / 64; ++i) {
        const int buf = i & 1;

        // T14: issue next tile's global loads first (drained by the barrier's vmcnt)
        if (i + 1 < Nn / 64) {
            const int n0n = (i + 1) * 64;
#pragma unroll
            for (int p = 0; p < 8; ++p)
                st[p] = *(const uint4*)&Vbg[(size_t)(e0 + p * 8 + e_l) * Nn + n0n + n8];
#pragma unroll
            for (int tt = 0; tt < 4; ++tt)
                kf_nxt[tt] = *(const f16x8*)&Kb[(size_t)(n0n + tt * 16 + l15) * PD + g * 8];
        }

        // QK^T swapped: lane: col m=l15 (wave's m-subtile), rows n=16tt+4g+r
        f32x4 s[4];
        const f32x4 zero = {0.f, 0.f, 0.f, 0.f};
#pragma unroll
        for (int tt = 0; tt < 4; ++tt)
            s[tt] = __builtin_amdgcn_mfma_f32_16x16x32_f16(kf_cur[tt], qf, zero, 0, 0, 0);
        if (i + 1 < Nn / 64) {
#pragma unroll
            for (int tt = 0; tt < 4; ++tt) kf_cur[tt] = kf_nxt[tt];
        }

        // online softmax for row m = w*16 + l15
        float tm = s[0][0];
#pragma unroll
        for (int tt = 0; tt < 4; ++tt)
#pragma unroll
            for (int r = 0; r < 4; ++r) tm = fmaxf(tm, s[tt][r]);
        tm = fmaxf(tm, __shfl_xor(tm, 16));
        tm = fmaxf(tm, __shfl_xor(tm, 32));
        const float nm    = fmaxf(run_m, tm);
        const float alpha = __builtin_amdgcn_exp2f((run_m - nm) * 1.44269504089f);
        run_m = nm;

        float p[4][4];
        float rs = 0.f;
#pragma unroll
        for (int tt = 0; tt < 4; ++tt)
#pragma unroll
            for (int r = 0; r < 4; ++r) {
                p[tt][r] = __builtin_amdgcn_exp2f((s[tt][r] - nm) * 1.44269504089f);
                rs += p[tt][r];
            }
        rs += __shfl_xor(rs, 16);
        rs += __shfl_xor(rs, 32);
        run_l = run_l * alpha + rs;

        // publish P (rows w*16+l15) and alpha
#pragma unroll
        for (int tt = 0; tt < 4; ++tt) {
            f16x4 h;
#pragma unroll
            for (int r = 0; r < 4; ++r) h[r] = (_Float16)p[tt][r];
            *(f16x4*)&Pb_lds[buf][(w * 16 + l15) * 64 + ((tt * 16 + 4 * g) ^ pmask)] = h;
        }
        if (g == 0) Ab[buf][w * 16 + l15] = alpha;

        __syncthreads();   // the ONE barrier: P+alpha visible; vmcnt drain covers prefetch

        // rescale acc by alpha of each lane's rows (skip when all 1.0)
        float4 af[4];
#pragma unroll
        for (int mt = 0; mt < 4; ++mt)
            af[mt] = *(const float4*)&Ab[buf][mt * 16 + 4 * g];
        bool need = false;
#pragma unroll
        for (int mt = 0; mt < 4; ++mt)
            need = need || af[mt].x != 1.f || af[mt].y != 1.f || af[mt].z != 1.f || af[mt].w != 1.f;
        if (__any(need)) {
#pragma unroll
            for (int mt = 0; mt < 4; ++mt)
#pragma unroll
                for (int et = 0; et < 4; ++et) {
                    acc[mt][et][0] *= af[mt].x; acc[mt][et][1] *= af[mt].y;
                    acc[mt][et][2] *= af[mt].z; acc[mt][et][3] *= af[mt].w;
                }
        }

        // stash next V tile into the other buffer (wave-private, no barrier)
        if (i + 1 < Nn / 64) {
#pragma unroll
            for (int p2 = 0; p2 < 8; ++p2)
                *(uint4*)&Vb_lds[buf ^ 1][(e0 + p2 * 8 + e_l) * 64 + (n8 ^ wsw)] = st[p2];
        }

        // PV: A = P[m][n] (all 64 m), B = V[n][e] (wave's 64 e)
        __builtin_amdgcn_s_setprio(1);
#pragma unroll
        for (int kk = 0; kk < 2; ++kk) {
            f16x8 pf[4];
#pragma unroll
            for (int mt = 0; mt < 4; ++mt)
                pf[mt] = *(const f16x8*)&Pb_lds[buf][(mt * 16 + l15) * 64 + ((kk * 32 + 8 * g) ^ pmask)];
#pragma unroll
            for (int et = 0; et < 4; ++et) {
                const int e = e0 + et * 16 + l15;
                const f16x8 vf = *(const f16x8*)&Vb_lds[buf][e * 64 + ((kk * 32 + 8 * g) ^ ((l15 & 7) << 3))];
#pragma unroll
                for (int mt = 0; mt < 4; ++mt)
                    acc[mt][et] = __builtin_amdgcn_mfma_f32_16x16x32_f16(pf[mt], vf, acc[mt][et], 0, 0, 0);
            }
        }
        __builtin_amdgcn_s_setprio(0);
    }

    // publish l, normalize, gamma, residual
    if (g == 0) Lb[w * 16 + l15] = run_l;
    __syncthreads();

    const float gm = gamma_p[0];
    float4 linv[4];
#pragma unroll
    for (int mt = 0; mt < 4; ++mt) {
        float4 lv = *(const float4*)&Lb[mt * 16 + 4 * g];
        linv[mt].x = 1.f / lv.x; linv[mt].y = 1.f / lv.y;
        linv[mt].z = 1.f / lv.z; linv[mt].w = 1.f / lv.w;
    }
#pragma unroll
    for (int mt = 0; mt < 4; ++mt)
#pragma unroll
        for (int et = 0; et < 4; ++et) {
            const int e = e0 + et * 16 + l15;
            const size_t idx = ((size_t)b * Cc + e) * Nn + (m0 + mt * 16 + 4 * g);
            const float4 xin = *(const float4*)&x[idx];
            float4 o;
            o.x = gm * acc[mt][et][0] * linv[mt].x + xin.x;
            o.y = gm * acc[mt][et][1] * linv[mt].y + xin.y;
            o.z = gm * acc[mt][et][2] * linv[mt].z + xin.z;
            o.w = gm * acc[mt][et][3] * linv[mt].w + xin.w;
            *(float4*)&out[idx] = o;
        }
}

extern "C" void kernel_launch(void* const* d_in, const int* in_sizes, int n_in,
                              void* d_out, int out_size, void* d_ws, size_t ws_size,
                              hipStream_t stream) {
    (void)in_sizes; (void)n_in; (void)out_size; (void)d_ws; (void)ws_size;
    const float* x  = (const float*)d_in[0];
    const float* Wq = (const float*)d_in[1];
    const float* bq = (const float*)d_in[2];
    const float* Wk = (const float*)d_in[3];
    const float* bk = (const float*)d_in[4];
    const float* Wv = (const float*)d_in[5];
    const float* bv = (const float*)d_in[6];
    const float* gm = (const float*)d_in[7];
    float* out = (float*)d_out;

    proj_kernel<<<256, 256, 0, stream>>>(x, Wq, bq, Wk, bk, Wv, bv);
    attn_kernel<<<256, 256, 0, stream>>>(x, gm, out);
}

// Round 3
// 144.272 us; speedup vs baseline: 1.7794x; 1.5177x over previous
//
#include <hip/hip_runtime.h>

typedef _Float16 half_t;
typedef __attribute__((ext_vector_type(8))) _Float16 f16x8;
typedef __attribute__((ext_vector_type(4))) _Float16 f16x4;
typedef __attribute__((ext_vector_type(4))) float f32x4;

#define DEVI __device__ __forceinline__

static constexpr int Bn = 4, Cc = 256, Nn = 4096, PD = 32;
static constexpr float L2E = 1.44269504089f;

// persistent f16 intermediates (module-scope device memory; fully rewritten every call)
__device__ half_t g_Q[(size_t)Bn * Nn * PD];   // [b][n][d]
__device__ half_t g_K[(size_t)Bn * Nn * PD];   // [b][n][d]  (= k^T)
__device__ half_t g_V[(size_t)Bn * Cc * Nn];   // [b][e][n]

DEVI f16x8 cvt8(float4 a, float4 b) {
    f16x8 r;
    r[0] = (_Float16)a.x; r[1] = (_Float16)a.y; r[2] = (_Float16)a.z; r[3] = (_Float16)a.w;
    r[4] = (_Float16)b.x; r[5] = (_Float16)b.y; r[6] = (_Float16)b.z; r[7] = (_Float16)b.w;
    return r;
}

// ---------------- projection: Q,K,V = W @ x (+bias), f16 outputs ----------------
__global__ __launch_bounds__(256, 1) void proj_kernel(
    const float* __restrict__ x,
    const float* __restrict__ Wq, const float* __restrict__ bq,
    const float* __restrict__ Wk, const float* __restrict__ bk,
    const float* __restrict__ Wv, const float* __restrict__ bv)
{
    __shared__ __align__(16) half_t xt[64 * 40];   // [n][c] tile, pad 32->40

    const int b    = blockIdx.x >> 6;
    const int n0   = (blockIdx.x & 63) * 64;
    const int t    = threadIdx.x;
    const int w    = t >> 6;
    const int lane = t & 63;
    const int l15  = lane & 15, g = lane >> 4;

    f32x4 qk_acc[4] = {};
    f32x4 v_acc[4][4] = {};

    const float* wrow_qk = (w < 2) ? (Wq + (size_t)(16 * w + l15) * Cc)
                                   : (Wk + (size_t)(16 * (w - 2) + l15) * Cc);

    for (int cs = 0; cs < 8; ++cs) {
        const int c0 = cs * 32;
        {
            const int nl = t & 63;
            const int cg = t >> 6;
            const float* xp = x + ((size_t)(b * Cc + c0 + cg * 8)) * Nn + n0 + nl;
            float f[8];
#pragma unroll
            for (int q = 0; q < 8; ++q) f[q] = xp[(size_t)q * Nn];
            f16x4 h0, h1;
#pragma unroll
            for (int q = 0; q < 4; ++q) { h0[q] = (_Float16)f[q]; h1[q] = (_Float16)f[q + 4]; }
            *(f16x4*)&xt[nl * 40 + cg * 8]     = h0;
            *(f16x4*)&xt[nl * 40 + cg * 8 + 4] = h1;
        }
        __syncthreads();

        f16x8 xf[4];
#pragma unroll
        for (int nf = 0; nf < 4; ++nf)
            xf[nf] = *(const f16x8*)&xt[(nf * 16 + l15) * 40 + g * 8];

        {
            const float* wp = wrow_qk + c0 + g * 8;
            const f16x8 af = cvt8(*(const float4*)wp, *(const float4*)(wp + 4));
#pragma unroll
            for (int nt = 0; nt < 4; ++nt)
                qk_acc[nt] = __builtin_amdgcn_mfma_f32_16x16x32_f16(af, xf[nt], qk_acc[nt], 0, 0, 0);
        }
#pragma unroll
        for (int et = 0; et < 4; ++et) {
            const int e = (w * 4 + et) * 16 + l15;
            const float* wp = Wv + (size_t)e * Cc + c0 + g * 8;
            const f16x8 wf = cvt8(*(const float4*)wp, *(const float4*)(wp + 4));
#pragma unroll
            for (int nf = 0; nf < 4; ++nf)
                v_acc[et][nf] = __builtin_amdgcn_mfma_f32_16x16x32_f16(xf[nf], wf, v_acc[et][nf], 0, 0, 0);
        }
        __syncthreads();
    }

    {
        const float* bias = (w < 2) ? bq : bk;
        const int dbase = 16 * (w & 1) + 4 * g;
        float bb[4];
#pragma unroll
        for (int r = 0; r < 4; ++r) bb[r] = bias[dbase + r];
        half_t* dst = (w < 2) ? g_Q : g_K;
#pragma unroll
        for (int nt = 0; nt < 4; ++nt) {
            const int n = n0 + nt * 16 + l15;
            f16x4 h;
#pragma unroll
            for (int r = 0; r < 4; ++r) h[r] = (_Float16)(qk_acc[nt][r] + bb[r]);
            *(f16x4*)&dst[((size_t)b * Nn + n) * PD + dbase] = h;
        }
    }
#pragma unroll
    for (int et = 0; et < 4; ++et) {
        const int e = (w * 4 + et) * 16 + l15;
        const float bve = bv[e];
#pragma unroll
        for (int nf = 0; nf < 4; ++nf) {
            const int n = n0 + nf * 16 + 4 * g;
            f16x4 h;
#pragma unroll
            for (int r = 0; r < 4; ++r) h[r] = (_Float16)(v_acc[et][nf][r] + bve);
            *(f16x4*)&g_V[((size_t)b * Cc + e) * Nn + n] = h;
        }
    }
}

// ---------------- fused flash attention + residual (v3) ----------------
// Grid 512 = [b:4][e-quarter:4][m-tile:32]; block = 128 m x 64 e, 4 waves.
// Wave w owns 32 m-rows (2 sub-tiles of 16) x all 64 e END-TO-END:
// QK + softmax + PV with wave-private P (LDS, no barrier). Only the shared
// V tile (8KB, double-buffered) needs the ONE barrier per KV tile.
// 2 blocks/CU (grid 512, LDS 32KB) -> 2 waves/SIMD for latency hiding.
__global__ __launch_bounds__(256, 1) void attn_kernel(
    const float* __restrict__ x, const float* __restrict__ gamma_p, float* __restrict__ out)
{
    __shared__ __align__(16) half_t Vb_lds[2][64 * 64];   // [buf][e_loc][n] swizzled, 16KB
    __shared__ __align__(16) half_t Pw_lds[4][32 * 64];   // per-wave [m_loc][n] swizzled, 16KB

    const int blk  = blockIdx.x;
    const int mt   = blk & 31;
    const int e4   = (blk >> 5) & 3;
    const int b    = blk >> 7;
    const int m0   = mt * 128;
    const int e0   = e4 * 64;

    const int t    = threadIdx.x;
    const int w    = t >> 6;
    const int lane = t & 63;
    const int l15  = lane & 15, g = lane >> 4;
    const int swz  = (l15 & 7) << 3;           // elem-granule XOR mask for P/V reads
    const int mbase = m0 + w * 32;

    const half_t* Kb  = g_K + (size_t)b * Nn * PD;
    const half_t* Vbg = g_V + (size_t)b * Cc * Nn;

    f16x8 qf[2];
#pragma unroll
    for (int m2 = 0; m2 < 2; ++m2)
        qf[m2] = *(const f16x8*)&g_Q[((size_t)b * Nn + mbase + m2 * 16 + l15) * PD + g * 8];

    // V staging geometry: thread t covers rows el0, el0+32 (2 x uint4)
    const int el0 = t >> 3;                    // 0..31
    const int n8  = (t & 7) * 8;

    f32x4 acc[2][4] = {};                      // [m2][et]; row m=4g+r, col e=et*16+l15
    float run_m[2] = {-1e30f, -1e30f};
    float run_l[2] = {0.f, 0.f};

    uint4 st[2];
    f16x8 kf[4], kf_nxt[4];

    // prologue: stage V tile 0, load K tile 0
#pragma unroll
    for (int p = 0; p < 2; ++p)
        st[p] = *(const uint4*)&Vbg[(size_t)(e0 + el0 + p * 32) * Nn + n8];
#pragma unroll
    for (int tt = 0; tt < 4; ++tt)
        kf[tt] = *(const f16x8*)&Kb[(size_t)(tt * 16 + l15) * PD + g * 8];
#pragma unroll
    for (int p = 0; p < 2; ++p) {
        const int el = el0 + p * 32;
        *(uint4*)&Vb_lds[0][el * 64 + (n8 ^ ((el & 7) << 3))] = st[p];
    }
    __syncthreads();

    for (int i = 0; i < Nn / 64; ++i) {
        const int buf = i & 1;
        const bool more = (i + 1 < Nn / 64);

        // T14: issue next tile's global loads first (covered by full iter of work)
        if (more) {
            const int n0n = (i + 1) * 64;
#pragma unroll
            for (int p = 0; p < 2; ++p)
                st[p] = *(const uint4*)&Vbg[(size_t)(e0 + el0 + p * 32) * Nn + n0n + n8];
#pragma unroll
            for (int tt = 0; tt < 4; ++tt)
                kf_nxt[tt] = *(const f16x8*)&Kb[(size_t)(n0n + tt * 16 + l15) * PD + g * 8];
        }

        // QK^T swapped: s[m2][tt] -> S[n=tt*16+4g+r][m=mbase+m2*16+l15]
        f32x4 s[2][4];
        const f32x4 zero = {0.f, 0.f, 0.f, 0.f};
#pragma unroll
        for (int m2 = 0; m2 < 2; ++m2)
#pragma unroll
            for (int tt = 0; tt < 4; ++tt)
                s[m2][tt] = __builtin_amdgcn_mfma_f32_16x16x32_f16(kf[tt], qf[m2], zero, 0, 0, 0);
        if (more) {
#pragma unroll
            for (int tt = 0; tt < 4; ++tt) kf[tt] = kf_nxt[tt];
        }

        // online softmax, rows m = mbase + m2*16 + l15
        float tm[2];
#pragma unroll
        for (int m2 = 0; m2 < 2; ++m2) {
            float v = s[m2][0][0];
#pragma unroll
            for (int tt = 0; tt < 4; ++tt)
#pragma unroll
                for (int r = 0; r < 4; ++r) v = fmaxf(v, s[m2][tt][r]);
            v = fmaxf(v, __shfl_xor(v, 16));
            v = fmaxf(v, __shfl_xor(v, 32));
            tm[m2] = v;
        }

        // T13 defer-max: only update max/rescale when growth > THR
        const bool upd = (tm[0] > run_m[0] + 8.f) || (tm[1] > run_m[1] + 8.f);
        float alpha[2] = {1.f, 1.f};
        if (__any(upd)) {
#pragma unroll
            for (int m2 = 0; m2 < 2; ++m2) {
                const float nm = fmaxf(run_m[m2], tm[m2]);
                alpha[m2] = __builtin_amdgcn_exp2f((run_m[m2] - nm) * L2E);
                run_m[m2] = nm;
            }
            // rescale acc rows m=4g+r
            float a4[2][4];
#pragma unroll
            for (int m2 = 0; m2 < 2; ++m2)
#pragma unroll
                for (int r = 0; r < 4; ++r) a4[m2][r] = __shfl(alpha[m2], 4 * g + r);
#pragma unroll
            for (int m2 = 0; m2 < 2; ++m2)
#pragma unroll
                for (int et = 0; et < 4; ++et)
#pragma unroll
                    for (int r = 0; r < 4; ++r) acc[m2][et][r] *= a4[m2][r];
        }

        // p = exp2((s - m)*log2e); row-sum; write P (wave-private, swizzled)
#pragma unroll
        for (int m2 = 0; m2 < 2; ++m2) {
            const float nms = run_m[m2] * L2E;
            float rs = 0.f;
#pragma unroll
            for (int tt = 0; tt < 4; ++tt) {
                f16x4 h;
#pragma unroll
                for (int r = 0; r < 4; ++r) {
                    const float pv = __builtin_amdgcn_exp2f(s[m2][tt][r] * L2E - nms);
                    rs += pv;
                    h[r] = (_Float16)pv;
                }
                *(f16x4*)&Pw_lds[w][(m2 * 16 + l15) * 64 + ((tt * 16 + 4 * g) ^ swz)] = h;
            }
            rs += __shfl_xor(rs, 16);
            rs += __shfl_xor(rs, 32);
            run_l[m2] = run_l[m2] * alpha[m2] + rs;
        }

        // PV: A = P[m][n] (wave-private), B = V[n][e] (shared tile)
        f16x8 pf[2][2];
#pragma unroll
        for (int m2 = 0; m2 < 2; ++m2)
#pragma unroll
            for (int kk = 0; kk < 2; ++kk)
                pf[m2][kk] = *(const f16x8*)&Pw_lds[w][(m2 * 16 + l15) * 64 + ((kk * 32 + 8 * g) ^ swz)];

        __builtin_amdgcn_s_setprio(1);
#pragma unroll
        for (int et = 0; et < 4; ++et) {
            const int el = et * 16 + l15;
#pragma unroll
            for (int kk = 0; kk < 2; ++kk) {
                const f16x8 vf = *(const f16x8*)&Vb_lds[buf][el * 64 + ((kk * 32 + 8 * g) ^ swz)];
                acc[0][et] = __builtin_amdgcn_mfma_f32_16x16x32_f16(pf[0][kk], vf, acc[0][et], 0, 0, 0);
                acc[1][et] = __builtin_amdgcn_mfma_f32_16x16x32_f16(pf[1][kk], vf, acc[1][et], 0, 0, 0);
            }
        }
        __builtin_amdgcn_s_setprio(0);

        // publish next V tile, then the ONE barrier
        if (more) {
#pragma unroll
            for (int p = 0; p < 2; ++p) {
                const int el = el0 + p * 32;
                *(uint4*)&Vb_lds[buf ^ 1][el * 64 + (n8 ^ ((el & 7) << 3))] = st[p];
            }
        }
        __syncthreads();
    }

    // epilogue: normalize, gamma, residual
    const float gm = gamma_p[0];
    float linv[2][4];
#pragma unroll
    for (int m2 = 0; m2 < 2; ++m2) {
        const float inv = 1.0f / run_l[m2];
#pragma unroll
        for (int r = 0; r < 4; ++r) linv[m2][r] = __shfl(inv, 4 * g + r);
    }
#pragma unroll
    for (int m2 = 0; m2 < 2; ++m2)
#pragma unroll
        for (int et = 0; et < 4; ++et) {
            const int e = e0 + et * 16 + l15;
            const size_t idx = ((size_t)b * Cc + e) * Nn + (mbase + m2 * 16 + 4 * g);
            const float4 xin = *(const float4*)&x[idx];
            float4 o;
            o.x = gm * acc[m2][et][0] * linv[m2][0] + xin.x;
            o.y = gm * acc[m2][et][1] * linv[m2][1] + xin.y;
            o.z = gm * acc[m2][et][2] * linv[m2][2] + xin.z;
            o.w = gm * acc[m2][et][3] * linv[m2][3] + xin.w;
            *(float4*)&out[idx] = o;
        }
}

extern "C" void kernel_launch(void* const* d_in, const int* in_sizes, int n_in,
                              void* d_out, int out_size, void* d_ws, size_t ws_size,
                              hipStream_t stream) {
    (void)in_sizes; (void)n_in; (void)out_size; (void)d_ws; (void)ws_size;
    const float* x  = (const float*)d_in[0];
    const float* Wq = (const float*)d_in[1];
    const float* bq = (const float*)d_in[2];
    const float* Wk = (const float*)d_in[3];
    const float* bk = (const float*)d_in[4];
    const float* Wv = (const float*)d_in[5];
    const float* bv = (const float*)d_in[6];
    const float* gm = (const float*)d_in[7];
    float* out = (float*)d_out;

    proj_kernel<<<256, 256, 0, stream>>>(x, Wq, bq, Wk, bk, Wv, bv);
    attn_kernel<<<512, 256, 0, stream>>>(x, gm, out);
}